// Round 1
// baseline (276.236 us; speedup 1.0000x reference)
//
#include <hip/hip_runtime.h>

// MoE combiner: out[i,:] = sum_e gates[i,e] * expert_outputs[e,:]
// expert_outputs: [64, 4096] f32   (d_in[0])
// gates:          [16384, 64] f32  (d_in[1], exactly top-2 nonzero per row)
// out:            [16384, 4096] f32
//
// Write-roofline bound (~256 MB out at ~6.4 TB/s achievable => ~43 us floor).
// Structure: ONE WAVE = ONE ROW. No LDS, no __syncthreads. Each wave:
//   - lane e reads gates[row][e] (coalesced 64-float read per wave)
//   - __ballot -> uniform 64-bit mask of nonzero gates
//   - e0/e1 from ffs/clz, gate values broadcast via __shfl (branch is
//     wave-uniform because the mask is wave-uniform)
//   - 16 independent load->fma->nontemporal-store iterations over the row
// Non-temporal stores keep the streaming 256 MB output from thrashing the
// 4 MB per-XCD L2, so the 1 MB expert table stays L2-resident and the
// ~512 MB of logical expert re-reads never hit HBM.

#define NUM_EXPERTS 64
#define D_MODEL 4096
#define NUM_IMAGES 16384
#define D4 (D_MODEL / 4)          // 1024 float4 per row
#define ROWS_PER_BLOCK 4          // 4 waves per 256-thread block

typedef float v4f __attribute__((ext_vector_type(4)));

__global__ __launch_bounds__(256) void moe_combine_kernel(
    const float* __restrict__ expert,   // [64, 4096]
    const float* __restrict__ gates,    // [16384, 64]
    float* __restrict__ out)            // [16384, 4096]
{
    const int wave = threadIdx.x >> 6;
    const int lane = threadIdx.x & 63;
    const int row  = blockIdx.x * ROWS_PER_BLOCK + wave;

    // Gates row is read exactly once; non-temporal load avoids polluting L2.
    const float g = __builtin_nontemporal_load(&gates[(size_t)row * NUM_EXPERTS + lane]);
    const unsigned long long m = __ballot(g != 0.0f);
    const int cnt = __popcll(m);

    const v4f* __restrict__ E = (const v4f*)expert;
    v4f* __restrict__ Orow = (v4f*)out + (size_t)row * D4;

    if (cnt == 2) {
        // Fast path: exactly top-2 nonzero (always, for this routing).
        // m is wave-uniform, so this branch is non-divergent and __shfl is safe.
        const int e0 = __ffsll(m) - 1;          // lowest set bit
        const int e1 = 63 - __clzll(m);         // highest set bit
        const float g0 = __shfl(g, e0);
        const float g1 = __shfl(g, e1);
        const v4f* __restrict__ E0 = E + (size_t)e0 * D4;
        const v4f* __restrict__ E1 = E + (size_t)e1 * D4;
        #pragma unroll 4
        for (int k = 0; k < D4 / 64; ++k) {
            const int c = lane + (k << 6);      // coalesced: 64 lanes x 16 B = 1 KB/instr
            const v4f acc = g0 * E0[c] + g1 * E1[c];
            __builtin_nontemporal_store(acc, &Orow[c]);
        }
    } else {
        // Generic fallback (cnt != 2), still correct. Wave-uniform trip count.
        for (int c = lane; c < D4; c += 64) {
            v4f acc = (v4f)(0.0f);
            unsigned long long mm = m;
            while (mm) {
                const int e = __ffsll(mm) - 1;
                mm &= mm - 1ull;
                const float ge = __shfl(g, e);
                acc += ge * E[(size_t)e * D4 + c];
            }
            __builtin_nontemporal_store(acc, &Orow[c]);
        }
    }
}

extern "C" void kernel_launch(void* const* d_in, const int* in_sizes, int n_in,
                              void* d_out, int out_size, void* d_ws, size_t ws_size,
                              hipStream_t stream) {
    const float* expert = (const float*)d_in[0];  // [64, 4096]
    const float* gates  = (const float*)d_in[1];  // [16384, 64]
    float* out = (float*)d_out;                   // [16384, 4096]

    dim3 grid(NUM_IMAGES / ROWS_PER_BLOCK);       // 4096 blocks, 1 wave per row
    dim3 block(256);
    moe_combine_kernel<<<grid, block, 0, stream>>>(expert, gates, out);
}